// Round 5
// baseline (289.031 us; speedup 1.0000x reference)
//
#include <hip/hip_runtime.h>

// Reaction-diffusion (vegetation NCA) single Euler step, fused.
// w' = w + (lap(w) - 0.2 w + 1.845 - U) * 1e-4,  U = w*b*(1+3b)
// b' = b + (0.05 lap(b) - 0.3 T b + 0.449 U) * 1e-4
// Laplacian: 5-point, replicate (edge) padding.
//
// R5: R2-R4 all latency-bound (HBM 21-29%, all pipes idle) -- one-shot
// blocks die after one tile, so each CU serially eats ~16 memory-latency
// stalls. Now: 1024 persistent blocks (4/CU, all co-resident under
// __launch_bounds__(256,4)), each walking 8 consecutive 2-row tiles with a
// register-rotating software pipeline: prefetch tile t+1 (6 f4 + 8 edge
// scalars; 2 halo rows reused in regs), sched_barrier, compute tile t,
// store. Waves keep ~7KB in flight continuously. Arithmetic order identical
// (absmax==0 in R2-R4).

namespace {
constexpr int IMGS = 16;
constexpr int H = 1024;
constexpr int W = 1024;
constexpr size_t PLANE = (size_t)H * W;
constexpr int RPB = 16;          // rows per block strip
constexpr int NT  = 8;           // 2-row tiles per block
}

typedef float f4 __attribute__((ext_vector_type(4)));

__device__ __forceinline__ void row_update(
    const f4 uw, const f4 cw, const f4 dw,
    const f4 ub, const f4 cb, const f4 db,
    const f4 cT, float elW, float erW, float elB, float erB,
    int lane, int x0, f4& ow4, f4& ob4)
{
    float wl = __shfl_up(cw.w, 1);
    float wr = __shfl_down(cw.x, 1);
    float bl = __shfl_up(cb.w, 1);
    float br = __shfl_down(cb.x, 1);
    if (lane == 0)  { wl = (x0 > 0)     ? elW : cw.x;  bl = (x0 > 0)     ? elB : cb.x; }
    if (lane == 63) { wr = (x0 + 4 < W) ? erW : cw.w;  br = (x0 + 4 < W) ? erB : cb.w; }

    // Same summation order as prior (bit-exact) rounds: u + d + l + r - 4c.
    f4 lw, lb;
    lw.x = uw.x + dw.x + wl   + cw.y - 4.0f * cw.x;
    lw.y = uw.y + dw.y + cw.x + cw.z - 4.0f * cw.y;
    lw.z = uw.z + dw.z + cw.y + cw.w - 4.0f * cw.z;
    lw.w = uw.w + dw.w + cw.z + wr   - 4.0f * cw.w;

    lb.x = ub.x + db.x + bl   + cb.y - 4.0f * cb.x;
    lb.y = ub.y + db.y + cb.x + cb.z - 4.0f * cb.y;
    lb.z = ub.z + db.z + cb.y + cb.w - 4.0f * cb.z;
    lb.w = ub.w + db.w + cb.z + br   - 4.0f * cb.w;

#pragma unroll
    for (int j = 0; j < 4; ++j) {
        const float up = cw[j] * cb[j] * (1.0f + 3.0f * cb[j]);
        ow4[j] = cw[j] + (lw[j] - 0.2f * cw[j] + 1.845f - up) * 1e-4f;
        ob4[j] = cb[j] + (0.05f * lb[j] - 0.3f * cT[j] * cb[j] + 0.449f * up) * 1e-4f;
    }
}

__global__ __launch_bounds__(256, 4) void nca_step(
    const float* __restrict__ wg, const float* __restrict__ bg,
    const float* __restrict__ Tg, float* __restrict__ owg,
    float* __restrict__ obg)
{
    // XCD-aware swizzle: 1024 blocks = 8 XCDs x 128; each XCD gets 2 whole
    // contiguous images so strip-boundary halo rows are L2-local.
    const int nwg = gridDim.x;
    const int cpx = nwg >> 3;                       // 128
    const int bid = blockIdx.x;
    const int swz = (bid & 7) * cpx + (bid >> 3);

    const int img = swz >> 6;                       // 64 strips per image
    const int rs  = (swz & 63) * RPB;
    const int t    = threadIdx.x;
    const int lane = t & 63;
    const int x0   = t << 2;

    const float* wp = wg + (size_t)img * PLANE;
    const float* bp = bg + (size_t)img * PLANE;
    const float* Tp = Tg + (size_t)img * PLANE;
    float* owp = owg + (size_t)img * PLANE;
    float* obp = obg + (size_t)img * PLANE;

    const bool pL = (lane == 0)  && (x0 > 0);       // wave-edge fixup lanes
    const bool pR = (lane == 63) && (x0 + 4 < W);

    // ---- prologue: tile 0 (rows rs, rs+1); buffer rows rs-1..rs+2 ----
    const int rm = (rs > 0) ? rs - 1 : 0;           // replicate at image top
    f4 wv0 = *(const f4*)(wp + (size_t)rm * W + x0);
    f4 wv1 = *(const f4*)(wp + (size_t)rs * W + x0);
    f4 wv2 = *(const f4*)(wp + (size_t)(rs + 1) * W + x0);
    f4 wv3 = *(const f4*)(wp + (size_t)(rs + 2) * W + x0);
    f4 bv0 = *(const f4*)(bp + (size_t)rm * W + x0);
    f4 bv1 = *(const f4*)(bp + (size_t)rs * W + x0);
    f4 bv2 = *(const f4*)(bp + (size_t)(rs + 1) * W + x0);
    f4 bv3 = *(const f4*)(bp + (size_t)(rs + 2) * W + x0);
    f4 tv0 = __builtin_nontemporal_load((const f4*)(Tp + (size_t)rs * W + x0));
    f4 tv1 = __builtin_nontemporal_load((const f4*)(Tp + (size_t)(rs + 1) * W + x0));

    float eWl0 = pL ? wp[(size_t)rs * W + x0 - 1]       : 0.0f;
    float eWl1 = pL ? wp[(size_t)(rs + 1) * W + x0 - 1] : 0.0f;
    float eWr0 = pR ? wp[(size_t)rs * W + x0 + 4]       : 0.0f;
    float eWr1 = pR ? wp[(size_t)(rs + 1) * W + x0 + 4] : 0.0f;
    float eBl0 = pL ? bp[(size_t)rs * W + x0 - 1]       : 0.0f;
    float eBl1 = pL ? bp[(size_t)(rs + 1) * W + x0 - 1] : 0.0f;
    float eBr0 = pR ? bp[(size_t)rs * W + x0 + 4]       : 0.0f;
    float eBr1 = pR ? bp[(size_t)(rs + 1) * W + x0 + 4] : 0.0f;

#pragma unroll
    for (int it = 0; it < NT; ++it) {
        const int r0 = rs + it * 2;

        // ---- prefetch tile it+1: rows r0+2, r0+3 (new w/b rows r0+3, r0+4) ----
        f4 nw0, nw1, nb0, nb1, nt0, nt1;
        float nWl0 = 0.0f, nWl1 = 0.0f, nWr0 = 0.0f, nWr1 = 0.0f;
        float nBl0 = 0.0f, nBl1 = 0.0f, nBr0 = 0.0f, nBr1 = 0.0f;
        if (it < NT - 1) {
            const int ra = r0 + 3;                          // <= 1023 always
            const int rb = (r0 + 4 < H) ? (r0 + 4) : (H - 1); // replicate bottom
            nw0 = *(const f4*)(wp + (size_t)ra * W + x0);
            nw1 = *(const f4*)(wp + (size_t)rb * W + x0);
            nb0 = *(const f4*)(bp + (size_t)ra * W + x0);
            nb1 = *(const f4*)(bp + (size_t)rb * W + x0);
            nt0 = __builtin_nontemporal_load((const f4*)(Tp + (size_t)(r0 + 2) * W + x0));
            nt1 = __builtin_nontemporal_load((const f4*)(Tp + (size_t)(r0 + 3) * W + x0));
            nWl0 = pL ? wp[(size_t)(r0 + 2) * W + x0 - 1] : 0.0f;
            nWl1 = pL ? wp[(size_t)(r0 + 3) * W + x0 - 1] : 0.0f;
            nWr0 = pR ? wp[(size_t)(r0 + 2) * W + x0 + 4] : 0.0f;
            nWr1 = pR ? wp[(size_t)(r0 + 3) * W + x0 + 4] : 0.0f;
            nBl0 = pL ? bp[(size_t)(r0 + 2) * W + x0 - 1] : 0.0f;
            nBl1 = pL ? bp[(size_t)(r0 + 3) * W + x0 - 1] : 0.0f;
            nBr0 = pR ? bp[(size_t)(r0 + 2) * W + x0 + 4] : 0.0f;
            nBr1 = pR ? bp[(size_t)(r0 + 3) * W + x0 + 4] : 0.0f;
        }

        // Pin boundary: prefetch issues stay above, compute stays below.
        __builtin_amdgcn_sched_barrier(0);

        // ---- compute tile it from registers loaded one iteration ago ----
        f4 ow0, ob0, ow1, ob1;
        row_update(wv0, wv1, wv2, bv0, bv1, bv2, tv0,
                   eWl0, eWr0, eBl0, eBr0, lane, x0, ow0, ob0);
        row_update(wv1, wv2, wv3, bv1, bv2, bv3, tv1,
                   eWl1, eWr1, eBl1, eBr1, lane, x0, ow1, ob1);

        const size_t o0 = (size_t)r0 * W + x0;
        __builtin_nontemporal_store(ow0, (f4*)(owp + o0));
        __builtin_nontemporal_store(ob0, (f4*)(obp + o0));
        __builtin_nontemporal_store(ow1, (f4*)(owp + o0 + W));
        __builtin_nontemporal_store(ob1, (f4*)(obp + o0 + W));

        // ---- rotate buffers (2 halo rows reused in registers) ----
        if (it < NT - 1) {
            wv0 = wv2; wv1 = wv3; wv2 = nw0; wv3 = nw1;
            bv0 = bv2; bv1 = bv3; bv2 = nb0; bv3 = nb1;
            tv0 = nt0; tv1 = nt1;
            eWl0 = nWl0; eWl1 = nWl1; eWr0 = nWr0; eWr1 = nWr1;
            eBl0 = nBl0; eBl1 = nBl1; eBr0 = nBr0; eBr1 = nBr1;
        }
    }
}

extern "C" void kernel_launch(void* const* d_in, const int* in_sizes, int n_in,
                              void* d_out, int out_size, void* d_ws, size_t ws_size,
                              hipStream_t stream) {
    const float* w = (const float*)d_in[0];
    const float* b = (const float*)d_in[1];
    const float* T = (const float*)d_in[2];
    float* ow = (float*)d_out;                      // w_new first (return order)
    float* ob = ow + (size_t)IMGS * PLANE;          // then b_new

    dim3 grid(IMGS * (H / RPB));                    // 1024 persistent blocks
    dim3 block(W / 4);                              // 256 threads x float4
    nca_step<<<grid, block, 0, stream>>>(w, b, T, ow, ob);
}